// Round 3
// baseline (883.374 us; speedup 1.0000x reference)
//
#include <hip/hip_runtime.h>
#include <stdint.h>

#define NWIN 4096
#define NTOK 49
#define CDIM 192
#define NH   6
#define HD   32

typedef __attribute__((ext_vector_type(8))) short short8;
typedef __attribute__((ext_vector_type(4))) float floatx4;
typedef unsigned short ushort_t;
typedef unsigned int uint32;

// LDS row strides in bf16 elements: multiples of 8 (16-B alignment for b128),
// dword-stride mod 32 == 4 -> <=2-way bank aliasing (free per m136).
#define XS_S  200   // x-staging / attention-output rows (49 x 200)
#define QK2_S 136   // per-pass q,k rows: 128 cols + 8 pad
#define P_S   72    // probability rows (cols 0..63 used, 49..63 zeroed)
#define VT_S  72    // V-transposed rows (2 heads x 32 d-rows, cols 0..63)

__device__ __forceinline__ ushort_t f2bf(float f) {
    uint32 u = __float_as_uint(f);
    u += 0x7fffu + ((u >> 16) & 1u);   // round-to-nearest-even
    return (ushort_t)(u >> 16);
}

// Pre-convert weights to bf16 and pre-gather rpe bias into [6][49][64] fp32.
__global__ void wmsa_prologue(const float* __restrict__ qkv_w,
                              const float* __restrict__ proj_w,
                              const float* __restrict__ rpe_table,
                              const int*   __restrict__ rpe_idx,
                              ushort_t* __restrict__ qkv_wb,
                              ushort_t* __restrict__ proj_wb,
                              float* __restrict__ biasws)
{
    int i = blockIdx.x * 256 + threadIdx.x;
    if (i < 110592) {
        qkv_wb[i] = f2bf(qkv_w[i]);
    } else if (i < 147456) {
        proj_wb[i - 110592] = f2bf(proj_w[i - 110592]);
    } else if (i < 147456 + NH * NTOK * 64) {
        int r = i - 147456;
        int h = r / (NTOK * 64);
        int rem = r - h * (NTOK * 64);
        int n = rem >> 6, m = rem & 63;
        biasws[r] = (m < NTOK) ? rpe_table[rpe_idx[n * NTOK + m] * NH + h] : 0.f;
    }
}

__global__ __launch_bounds__(256)
void wmsa_mfma(const float* __restrict__ x,
               const ushort_t* __restrict__ qkv_wb,
               const float* __restrict__ qkv_b,
               const ushort_t* __restrict__ proj_wb,
               const float* __restrict__ proj_b,
               const float* __restrict__ biasws,
               float* __restrict__ out)
{
    // reg0 holds x (bf16) during fragment preload, then attention output.
    __shared__ alignas(16) ushort_t reg0[NTOK * XS_S];    // 19600 B
    __shared__ alignas(16) ushort_t qkvs[NTOK * QK2_S];   // 13328 B
    __shared__ alignas(16) ushort_t Pb[64 * P_S];         //  9216 B
    __shared__ alignas(16) ushort_t Vt[64 * VT_S];        //  9216 B (total 51360 -> 3 blk/CU)

    const int b    = blockIdx.x;
    const int t    = threadIdx.x;
    const int w    = t >> 6;      // wave 0..3
    const int lane = t & 63;
    const int quad = lane >> 4;   // MFMA k-group
    const int c    = lane & 15;   // MFMA row/col within group
    const float scale = 0.17677669529663687f;   // 32^-0.5

    const float* xb = x + (size_t)b * (NTOK * CDIM);

    // ---------- stage x -> bf16 LDS (coalesced float4) ----------
    for (int i = t; i < (NTOK * CDIM) / 4; i += 256) {
        int e = i * 4;
        int n = e / CDIM, d = e - n * CDIM;
        float4 v = *(const float4*)(xb + e);
        ushort_t* p = &reg0[n * XS_S + d];
        p[0] = f2bf(v.x); p[1] = f2bf(v.y); p[2] = f2bf(v.z); p[3] = f2bf(v.w);
    }
    __syncthreads();

    // ---------- preload all x fragments into registers ----------
    // A/B layout (16x16x32): idx = lane&15, k = quad*8 + j  [m120-verified]
    short8 afr[4][6];
    #pragma unroll
    for (int mt = 0; mt < 4; ++mt) {
        int row = mt * 16 + c;   // rows >=49: stale LDS, confined to masked outputs
        #pragma unroll
        for (int ks = 0; ks < 6; ++ks)
            afr[mt][ks] = *(const short8*)&reg0[row * XS_S + ks * 32 + quad * 8];
    }
    // no extra sync: afr stays in registers; reg0 attn-out writes come later

    for (int pass = 0; pass < 3; ++pass) {
        // ---------- q,k GEMM: C = x @ W^T, 8 col-tiles of 16 ----------
        for (int e = w; e < 8; e += 4) {
            int s_idx = e >> 2;                // 0=q 1=k
            int hh    = (e >> 1) & 1;
            int half  = e & 1;
            int h     = pass * 2 + hh;
            int jrow  = s_idx * CDIM + h * HD + half * 16 + c;
            const ushort_t* bp = qkv_wb + (size_t)jrow * CDIM + quad * 8;

            floatx4 z = {0.f, 0.f, 0.f, 0.f};
            floatx4 acc[4];
            #pragma unroll
            for (int mt = 0; mt < 4; ++mt) acc[mt] = z;
            #pragma unroll
            for (int ks = 0; ks < 6; ++ks) {
                short8 bf = *(const short8*)(bp + ks * 32);
                #pragma unroll
                for (int mt = 0; mt < 4; ++mt)
                    acc[mt] = __builtin_amdgcn_mfma_f32_16x16x32_bf16(
                        afr[mt][ks], bf, acc[mt], 0, 0, 0);
            }
            float bias = qkv_b[jrow];
            float mul  = (s_idx == 0) ? scale : 1.f;
            int ecol   = s_idx * 64 + hh * 32 + half * 16 + c;
            #pragma unroll
            for (int mt = 0; mt < 4; ++mt) {
                #pragma unroll
                for (int r = 0; r < 4; ++r) {
                    int n = mt * 16 + quad * 4 + r;   // C: col=lane&15, row=quad*4+reg
                    if (n < NTOK)
                        qkvs[n * QK2_S + ecol] = f2bf((acc[mt][r] + bias) * mul);
                }
            }
        }

        // ---------- v GEMM, swapped operands: C[d][tok] = V^T directly ----------
        for (int vt = w; vt < 16; vt += 4) {
            int hh    = vt >> 3;
            int dtile = (vt >> 2) & 1;
            int ttile = vt & 3;
            int h     = pass * 2 + hh;
            const ushort_t* ap = qkv_wb
                + (size_t)(2 * CDIM + h * HD + dtile * 16 + c) * CDIM + quad * 8;

            floatx4 acc = {0.f, 0.f, 0.f, 0.f};
            #pragma unroll
            for (int ks = 0; ks < 6; ++ks) {
                short8 af = *(const short8*)(ap + ks * 32);   // A: m=d, k
                acc = __builtin_amdgcn_mfma_f32_16x16x32_bf16(
                    af, afr[ttile][ks], acc, 0, 0, 0);        // B: n=tok, k
            }
            int tok = ttile * 16 + c;
            #pragma unroll
            for (int r = 0; r < 4; ++r) {
                int d = dtile * 16 + quad * 4 + r;
                float bias = qkv_b[2 * CDIM + h * HD + d];
                Vt[(hh * HD + d) * VT_S + tok] =
                    (tok < NTOK) ? f2bf(acc[r] + bias) : (ushort_t)0;
            }
        }
        __syncthreads();   // qkvs + Vt ready for all waves

        // ---------- attention: 2 heads, barrier-free (Pb is wave-private) ----------
        for (int hh = 0; hh < 2; ++hh) {
            int h = pass * 2 + hh;

            // scores: wave w owns query rows w*16..w*16+15
            short8 aq = *(const short8*)&qkvs[(w * 16 + c) * QK2_S + hh * 32 + quad * 8];
            floatx4 sacc[4];
            #pragma unroll
            for (int nt = 0; nt < 4; ++nt) {
                short8 bk = *(const short8*)
                    &qkvs[(nt * 16 + c) * QK2_S + 64 + hh * 32 + quad * 8];
                floatx4 z = {0.f, 0.f, 0.f, 0.f};
                sacc[nt] = __builtin_amdgcn_mfma_f32_16x16x32_bf16(aq, bk, z, 0, 0, 0);
            }

            // in-register softmax: row n = w*16+quad*4+r lives across the 16
            // lanes of this quad -> shfl_xor 1/2/4/8.
            const float* bpb = biasws + h * (NTOK * 64);
            #pragma unroll
            for (int r = 0; r < 4; ++r) {
                int n  = w * 16 + quad * 4 + r;
                int nc = (n < NTOK) ? n : (NTOK - 1);
                float sv[4];
                #pragma unroll
                for (int nt = 0; nt < 4; ++nt) {
                    int col = nt * 16 + c;
                    float bias = bpb[nc * 64 + col];
                    sv[nt] = (col < NTOK) ? (sacc[nt][r] + bias) : -1e30f;
                }
                float m0 = fmaxf(fmaxf(sv[0], sv[1]), fmaxf(sv[2], sv[3]));
                m0 = fmaxf(m0, __shfl_xor(m0, 1));
                m0 = fmaxf(m0, __shfl_xor(m0, 2));
                m0 = fmaxf(m0, __shfl_xor(m0, 4));
                m0 = fmaxf(m0, __shfl_xor(m0, 8));
                float ex[4], s0 = 0.f;
                #pragma unroll
                for (int nt = 0; nt < 4; ++nt) { ex[nt] = __expf(sv[nt] - m0); s0 += ex[nt]; }
                s0 += __shfl_xor(s0, 1);
                s0 += __shfl_xor(s0, 2);
                s0 += __shfl_xor(s0, 4);
                s0 += __shfl_xor(s0, 8);
                float inv = 1.f / s0;
                if (n < NTOK) {
                    #pragma unroll
                    for (int nt = 0; nt < 4; ++nt)   // cols 49..63 -> exact 0
                        Pb[n * P_S + nt * 16 + c] = f2bf(ex[nt] * inv);
                }
            }

            // PV: [16x64] @ [64x32] per wave; same-wave Pb dependency (lgkmcnt only)
            floatx4 z2 = {0.f, 0.f, 0.f, 0.f};
            floatx4 oacc[2]; oacc[0] = z2; oacc[1] = z2;
            #pragma unroll
            for (int ks = 0; ks < 2; ++ks) {
                short8 ap = *(const short8*)&Pb[(w * 16 + c) * P_S + ks * 32 + quad * 8];
                #pragma unroll
                for (int nt = 0; nt < 2; ++nt) {
                    short8 bv = *(const short8*)
                        &Vt[(hh * HD + nt * 16 + c) * VT_S + ks * 32 + quad * 8];
                    oacc[nt] = __builtin_amdgcn_mfma_f32_16x16x32_bf16(ap, bv, oacc[nt], 0, 0, 0);
                }
            }
            #pragma unroll
            for (int nt = 0; nt < 2; ++nt) {
                #pragma unroll
                for (int r = 0; r < 4; ++r) {
                    int n = w * 16 + quad * 4 + r;
                    if (n < NTOK)
                        reg0[n * XS_S + h * HD + nt * 16 + c] = f2bf(oacc[nt][r]);
                }
            }
        }
        __syncthreads();   // protect qkvs/Vt for next pass; final one covers proj
    }

    // ---------- output projection: [49x192] @ [192x192]^T ----------
    short8 aof[4][6];
    #pragma unroll
    for (int mt = 0; mt < 4; ++mt) {
        int row = mt * 16 + c;
        #pragma unroll
        for (int ks = 0; ks < 6; ++ks)
            aof[mt][ks] = *(const short8*)&reg0[row * XS_S + ks * 32 + quad * 8];
    }
    for (int nt = w; nt < 12; nt += 4) {
        int j = nt * 16 + c;
        const ushort_t* bp = proj_wb + (size_t)j * CDIM + quad * 8;
        floatx4 z = {0.f, 0.f, 0.f, 0.f};
        floatx4 acc[4];
        #pragma unroll
        for (int mt = 0; mt < 4; ++mt) acc[mt] = z;
        #pragma unroll
        for (int ks = 0; ks < 6; ++ks) {
            short8 bf = *(const short8*)(bp + ks * 32);
            #pragma unroll
            for (int mt = 0; mt < 4; ++mt)
                acc[mt] = __builtin_amdgcn_mfma_f32_16x16x32_bf16(
                    aof[mt][ks], bf, acc[mt], 0, 0, 0);
        }
        float pb = proj_b[j];
        #pragma unroll
        for (int mt = 0; mt < 4; ++mt) {
            #pragma unroll
            for (int r = 0; r < 4; ++r) {
                int n = mt * 16 + quad * 4 + r;
                if (n < NTOK)
                    out[((size_t)b * NTOK + n) * CDIM + j] = acc[mt][r] + pb;
            }
        }
    }
}

extern "C" void kernel_launch(void* const* d_in, const int* in_sizes, int n_in,
                              void* d_out, int out_size, void* d_ws, size_t ws_size,
                              hipStream_t stream)
{
    const float* x      = (const float*)d_in[0];
    const float* qkv_w  = (const float*)d_in[1];
    const float* qkv_b  = (const float*)d_in[2];
    const float* proj_w = (const float*)d_in[3];
    const float* proj_b = (const float*)d_in[4];
    const float* rpe_t  = (const float*)d_in[5];
    const int*   rpe_i  = (const int*)d_in[6];
    float*       o      = (float*)d_out;

    // workspace: qkv_w bf16 | proj_w bf16 | bias fp32 [6][49][64]
    ushort_t* qkv_wb  = (ushort_t*)d_ws;
    ushort_t* proj_wb = qkv_wb + 110592;
    float*    biasws  = (float*)((char*)d_ws + (110592 + 36864) * sizeof(ushort_t));

    int tot = 147456 + NH * NTOK * 64;
    wmsa_prologue<<<dim3((tot + 255) / 256), dim3(256), 0, stream>>>(
        qkv_w, proj_w, rpe_t, rpe_i, qkv_wb, proj_wb, biasws);
    wmsa_mfma<<<dim3(NWIN), dim3(256), 0, stream>>>(
        x, qkv_wb, qkv_b, proj_wb, proj_b, biasws, o);
}